// Round 6
// baseline (509.224 us; speedup 1.0000x reference)
//
#include <hip/hip_runtime.h>

#define B_ 8
#define C_ 256
#define H_ 128
#define W_ 128
#define NW_ 512
#define HW_ (H_*W_)
#define EPS_ 1e-5f

typedef __attribute__((ext_vector_type(8))) short bf16x8;
typedef __attribute__((ext_vector_type(4))) float f32x4;

// RNE float -> bf16
__device__ __forceinline__ unsigned short f2bf(float f) {
  unsigned u = __float_as_uint(f);
  u += 0x7fffu + ((u >> 16) & 1u);
  return (unsigned short)(u >> 16);
}
__device__ __forceinline__ float bflo(unsigned u) { return __uint_as_float(u << 16); }
__device__ __forceinline__ float bfhi(unsigned u) { return __uint_as_float(u & 0xffff0000u); }

// ---------- BN stats, two-stage ----------
__global__ __launch_bounds__(256)
void bn_partial(const float* __restrict__ x, float* __restrict__ psum,
                float* __restrict__ psq) {
  const int b = blockIdx.x, c = blockIdx.y, tid = threadIdx.x;
  const float4* p = (const float4*)(x + (size_t)(b*C_ + c) * HW_);
  float s = 0.f, s2 = 0.f;
  #pragma unroll
  for (int i = 0; i < 16; ++i) {
    float4 v = p[tid + i*256];
    s  += v.x + v.y + v.z + v.w;
    s2 += v.x*v.x + v.y*v.y + v.z*v.z + v.w*v.w;
  }
  #pragma unroll
  for (int off = 32; off > 0; off >>= 1) {
    s  += __shfl_down(s, off);
    s2 += __shfl_down(s2, off);
  }
  __shared__ float rs[4], rq[4];
  if ((tid & 63) == 0) { rs[tid >> 6] = s; rq[tid >> 6] = s2; }
  __syncthreads();
  if (tid == 0) {
    float S = rs[0]+rs[1]+rs[2]+rs[3], S2 = rq[0]+rq[1]+rq[2]+rq[3];
    psum[c*B_ + b] = S;
    psq [c*B_ + b] = S2;
  }
}

__global__ __launch_bounds__(256)
void bn_final(float* __restrict__ wsf, const float* __restrict__ gamma,
              const float* __restrict__ beta) {
  const int c = threadIdx.x;
  float S = 0.f, S2 = 0.f;
  #pragma unroll
  for (int b = 0; b < B_; ++b) { S += wsf[512 + c*B_ + b]; S2 += wsf[2560 + c*B_ + b]; }
  const float n = (float)(B_*HW_);
  float mean = S / n;
  float var  = S2 / n - mean*mean;
  float scl  = gamma[c] * rsqrtf(var + EPS_);
  wsf[c]       = scl;
  wsf[C_ + c]  = beta[c] - mean*scl;
}

// ---------- w1 -> bf16 A-fragment table ----------
__global__ __launch_bounds__(64)
void w1prep(const float* __restrict__ w1, ushort* __restrict__ w1f) {
  const int l15 = threadIdx.x & 15, quad = threadIdx.x >> 4;
  const int mtG = blockIdx.x >> 4, ks = blockIdx.x & 15;
  const float* src = w1 + (size_t)(mtG*16 + l15)*NW_ + ks*32 + quad*8;
  float4 f0 = *(const float4*)src, f1 = *(const float4*)(src + 4);
  union { unsigned u[4]; uint4 q; } cv;
  cv.u[0] = (unsigned)f2bf(f0.x) | ((unsigned)f2bf(f0.y) << 16);
  cv.u[1] = (unsigned)f2bf(f0.z) | ((unsigned)f2bf(f0.w) << 16);
  cv.u[2] = (unsigned)f2bf(f1.x) | ((unsigned)f2bf(f1.y) << 16);
  cv.u[3] = (unsigned)f2bf(f1.z) | ((unsigned)f2bf(f1.w) << 16);
  ((uint4*)w1f)[blockIdx.x*64 + threadIdx.x] = cv.q;
}

// ---------- fused: BN-apply + dw3x3 + relu + 1x1 (MFMA) + bias + residual ----------
// BARRIER-FREE main loop (round-6). Diagnosis r4/r5: nothing saturated (VALU 32%,
// LDS ~36%, HBM 54% of share, MFMA 10%) and latency tweaks were null -> the wall is
// barrier lockstep with only 3 blocks/CU. Restructure: each wave owns ONE output row
// (16 px). Lane (quad,l15) computes y[o=quad*8+j][px=l15] (4 cin x 2 mult, needs only
// xn rows wv-1..wv+1) -> dwconv result IS the MFMA B-fragment, in registers. No s_yT,
// no cross-wave dependency, no __syncthreads in the k-loop (one at start for tables).
// Per chunk each wave runs all 16 M-tiles: acc[16] f32x4 = 64 AGPR (b1 folded into
// acc init). Wave-private xn slabs [16ch][3r][24+pad], dbuf; ch-stride 76 floats ->
// 2-way banks max (free). Weight pairs interleaved bf16 [cin][tap][2]: one bflo/bfhi
// per tap feeds both multiplier FMAs; 3 broadcast LDS reads/ci.
// LDS = 38912 + 12288 + 2048 = 53248 B -> 3 blocks/CU at __launch_bounds__(256,3).
template<bool PREW1>
__global__ __launch_bounds__(256, 3)
void fused_mfma(const float* __restrict__ x, const float* __restrict__ lbpw,
                const float* __restrict__ w1raw, const ushort* __restrict__ w1f,
                const float* __restrict__ b1, const float* __restrict__ sc_sh,
                float* __restrict__ out) {
  const int tid  = threadIdx.x;
  const int b    = blockIdx.z;
  const int h0   = blockIdx.y * 4;
  const int w0   = blockIdx.x * 16;
  const int wv   = tid >> 6;
  const int lane = tid & 63;
  const int l15  = lane & 15;
  const int quad = lane >> 4;

  __shared__ float  s_scale[C_];
  __shared__ float  s_shift[C_];
  __shared__ __align__(16) float  s_xn[2][4][1216];   // dbuf, per-wave slab: 16ch x (3r x 24 + 4 pad)
  __shared__ __align__(16) ushort s_wp[256][24];      // lbp pairs: [cin][tap]{o_even,o_odd} bf16

  s_scale[tid] = sc_sh[tid];
  s_shift[tid] = sc_sh[C_ + tid];
  {
    const float* wp0 = lbpw + (size_t)(2*tid)*9;
    #pragma unroll
    for (int t = 0; t < 9; ++t) {
      s_wp[tid][2*t]   = f2bf(wp0[t]);
      s_wp[tid][2*t+1] = f2bf(wp0[9 + t]);
    }
  }

  // ---- wave-private staging geometry (rows h0+wv-1 .. h0+wv+1) ----
  const int hbase = h0 + wv - 1;
  // interior: 16ch x 3r x 4 float4 = 192 slots -> 3/lane
  int gI[3], lI[3], cIdx[3]; unsigned mI = 0;
  #pragma unroll
  for (int k = 0; k < 3; ++k) {
    const int slot = lane + 64*k;
    const int ch = slot / 12;
    const int rem = slot - ch*12;
    const int r = rem >> 2, q = rem & 3;
    cIdx[k] = ch;
    lI[k] = ch*76 + r*24 + 4 + q*4;
    const int h = hbase + r;
    gI[k] = ch*HW_ + h*W_ + w0 + q*4;
    if (h >= 0 && h < H_) mI |= (1u << k);
  }
  // halo: 16ch x 3r x 2 sides = 96 slots -> lanes 0..63 slot lane, lanes 0..31 slot lane+64
  int gH[2], lH[2], cHx[2]; unsigned mH = 0, eH = 0;
  #pragma unroll
  for (int k = 0; k < 2; ++k) {
    const int slot = lane + 64*k;
    gH[k] = 0; lH[k] = 0; cHx[k] = 0;
    if (slot < 96) {
      eH |= (1u << k);
      const int ch = slot / 6;
      const int rem = slot - ch*6;
      const int r = rem >> 1, side = rem & 1;
      cHx[k] = ch;
      lH[k] = ch*76 + r*24 + (side ? 20 : 3);
      const int h = hbase + r;
      const int w = w0 + (side ? 16 : -1);
      gH[k] = ch*HW_ + h*W_ + w;
      if (h >= 0 && h < H_ && w >= 0 && w < W_) mH |= (1u << k);
    }
  }
  // pre-zero invalid slots in both buffers (own slab, never rewritten)
  {
    float* s0 = &s_xn[0][wv][0];
    float* s1 = &s_xn[1][wv][0];
    const float4 z4 = {0.f, 0.f, 0.f, 0.f};
    #pragma unroll
    for (int k = 0; k < 3; ++k)
      if (!(mI & (1u << k))) { *(float4*)(s0 + lI[k]) = z4; *(float4*)(s1 + lI[k]) = z4; }
    #pragma unroll
    for (int k = 0; k < 2; ++k)
      if ((eH & (1u << k)) && !(mH & (1u << k))) { s0[lH[k]] = 0.f; s1[lH[k]] = 0.f; }
  }

  // ---- acc init = b1 (folded bias) ----
  f32x4 acc[16];
  #pragma unroll
  for (int mt = 0; mt < 16; ++mt)
    acc[mt] = *(const f32x4*)(b1 + mt*16 + quad*4);

  __syncthreads();   // tables visible — the ONLY block barrier

  // ---- prologue: stage chunk 0 into buffer 0 (own slab) ----
  {
    const float* xc = x + (size_t)(b*C_) * HW_;
    float* sb = &s_xn[0][wv][0];
    #pragma unroll
    for (int k = 0; k < 3; ++k) if (mI & (1u << k)) {
      const float4 t = *(const float4*)(xc + gI[k]);
      const float sc = s_scale[cIdx[k]], sh = s_shift[cIdx[k]];
      float4 o; o.x = fmaf(t.x, sc, sh); o.y = fmaf(t.y, sc, sh);
                o.z = fmaf(t.z, sc, sh); o.w = fmaf(t.w, sc, sh);
      *(float4*)(sb + lI[k]) = o;
    }
    #pragma unroll
    for (int k = 0; k < 2; ++k) if (mH & (1u << k))
      sb[lH[k]] = fmaf(xc[gH[k]], s_scale[cHx[k]], s_shift[cHx[k]]);
  }

  #pragma unroll 2
  for (int kc = 0; kc < 16; ++kc) {
    const int p = kc & 1;

    // ---- A: issue raw x loads for chunk kc+1 (consumed at D) ----
    float4 rA0 = {0,0,0,0}, rA1 = {0,0,0,0}, rA2 = {0,0,0,0};
    float rH0 = 0.f, rH1 = 0.f;
    if (kc < 15) {
      const float* xc = x + (size_t)(b*C_ + (kc+1)*16) * HW_;
      if (mI & 1u) rA0 = *(const float4*)(xc + gI[0]);
      if (mI & 2u) rA1 = *(const float4*)(xc + gI[1]);
      if (mI & 4u) rA2 = *(const float4*)(xc + gI[2]);
      if (mH & 1u) rH0 = xc[gH[0]];
      if (mH & 2u) rH1 = xc[gH[1]];
    }

    // ---- B: dwconv chunk kc -> B-fragment in registers ----
    float a[8];
    #pragma unroll
    for (int j = 0; j < 8; ++j) a[j] = 0.f;
    {
      const float* sb = &s_xn[p][wv][0];
      #pragma unroll
      for (int ci = 0; ci < 4; ++ci) {
        const int cin = quad*4 + ci;
        const ushort* wr = &s_wp[kc*16 + cin][0];
        const uint4 wq  = *(const uint4*)(wr);        // taps 0..3 (pair words)
        const uint4 wq2 = *(const uint4*)(wr + 8);    // taps 4..7
        const unsigned w8 = *(const unsigned*)(wr + 16); // tap 8
        const unsigned wtap[9] = { wq.x, wq.y, wq.z, wq.w,
                                   wq2.x, wq2.y, wq2.z, wq2.w, w8 };
        const float* xb = sb + cin*76 + 3 + l15;
        float a0 = 0.f, a1 = 0.f;
        #pragma unroll
        for (int di = 0; di < 3; ++di)
          #pragma unroll
          for (int dj = 0; dj < 3; ++dj) {
            const unsigned wd = wtap[di*3 + dj];
            const float v = xb[di*24 + dj];
            a0 = fmaf(bflo(wd), v, a0);
            a1 = fmaf(bfhi(wd), v, a1);
          }
        a[2*ci]   = a0;
        a[2*ci+1] = a1;
      }
    }
    union { unsigned u[4]; bf16x8 v; } yv;
    #pragma unroll
    for (int t = 0; t < 4; ++t)
      yv.u[t] = (unsigned)f2bf(fmaxf(a[2*t], 0.f)) |
                ((unsigned)f2bf(fmaxf(a[2*t+1], 0.f)) << 16);
    const bf16x8 bfr = yv.v;

    // ---- C: MFMA all 16 M-tiles (K=32 of this chunk) ----
    #pragma unroll
    for (int mt = 0; mt < 16; ++mt) {
      bf16x8 afr;
      if constexpr (PREW1) {
        union { uint4 q; bf16x8 v; } cv;
        cv.q = *(const uint4*)(w1f + (size_t)((mt*16 + kc)*64 + lane)*8);
        afr = cv.v;
      } else {
        const float* wp = w1raw + (size_t)(mt*16 + l15)*NW_ + kc*32 + quad*8;
        const float4 f0 = *(const float4*)wp;
        const float4 f1 = *(const float4*)(wp + 4);
        union { unsigned u[4]; bf16x8 v; } cv;
        cv.u[0] = (unsigned)f2bf(f0.x) | ((unsigned)f2bf(f0.y) << 16);
        cv.u[1] = (unsigned)f2bf(f0.z) | ((unsigned)f2bf(f0.w) << 16);
        cv.u[2] = (unsigned)f2bf(f1.x) | ((unsigned)f2bf(f1.y) << 16);
        cv.u[3] = (unsigned)f2bf(f1.z) | ((unsigned)f2bf(f1.w) << 16);
        afr = cv.v;
      }
      acc[mt] = __builtin_amdgcn_mfma_f32_16x16x32_bf16(afr, bfr, acc[mt], 0, 0, 0);
    }

    // ---- D: transform staged regs (chunk kc+1) -> own slab [p^1] ----
    if (kc < 15) {
      const int c1 = (kc + 1) * 16;
      float* sb = &s_xn[p ^ 1][wv][0];
      if (mI & 1u) {
        const float sc = s_scale[c1 + cIdx[0]], sh = s_shift[c1 + cIdx[0]];
        float4 o; o.x = fmaf(rA0.x, sc, sh); o.y = fmaf(rA0.y, sc, sh);
                  o.z = fmaf(rA0.z, sc, sh); o.w = fmaf(rA0.w, sc, sh);
        *(float4*)(sb + lI[0]) = o;
      }
      if (mI & 2u) {
        const float sc = s_scale[c1 + cIdx[1]], sh = s_shift[c1 + cIdx[1]];
        float4 o; o.x = fmaf(rA1.x, sc, sh); o.y = fmaf(rA1.y, sc, sh);
                  o.z = fmaf(rA1.z, sc, sh); o.w = fmaf(rA1.w, sc, sh);
        *(float4*)(sb + lI[1]) = o;
      }
      if (mI & 4u) {
        const float sc = s_scale[c1 + cIdx[2]], sh = s_shift[c1 + cIdx[2]];
        float4 o; o.x = fmaf(rA2.x, sc, sh); o.y = fmaf(rA2.y, sc, sh);
                  o.z = fmaf(rA2.z, sc, sh); o.w = fmaf(rA2.w, sc, sh);
        *(float4*)(sb + lI[2]) = o;
      }
      if (mH & 1u) sb[lH[0]] = fmaf(rH0, s_scale[c1 + cHx[0]], s_shift[c1 + cHx[0]]);
      if (mH & 2u) sb[lH[1]] = fmaf(rH1, s_scale[c1 + cHx[1]], s_shift[c1 + cHx[1]]);
    }
  }

  // ---- epilogue: + raw-x residual (b1 already folded into acc init) ----
  const int hrow = h0 + wv;
  #pragma unroll
  for (int mt = 0; mt < 16; ++mt) {
    #pragma unroll
    for (int i = 0; i < 4; ++i) {
      const int ch = mt*16 + quad*4 + i;
      const size_t o = ((size_t)(b*C_ + ch)*H_ + hrow)*W_ + (w0 + l15);
      out[o] = acc[mt][i] + x[o];
    }
  }
}

extern "C" void kernel_launch(void* const* d_in, const int* in_sizes, int n_in,
                              void* d_out, int out_size, void* d_ws, size_t ws_size,
                              hipStream_t stream) {
  const float* x     = (const float*)d_in[0];
  const float* gamma = (const float*)d_in[1];
  const float* beta  = (const float*)d_in[2];
  const float* lbpw  = (const float*)d_in[3];
  const float* w1    = (const float*)d_in[4];
  const float* b1    = (const float*)d_in[5];
  float* out = (float*)d_out;

  // ws layout (floats): [0,256) scale | [256,512) shift | [512,2560) psum |
  //                     [2560,4608) psq | byte 18432: w1 bf16 frag table (256 KB)
  float* wsf = (float*)d_ws;
  ushort* w1f = (ushort*)((char*)d_ws + 18432);
  const bool pre = ws_size >= (size_t)(18432 + 262144);

  bn_partial<<<dim3(B_, C_), 256, 0, stream>>>(x, wsf + 512, wsf + 2560);
  bn_final<<<1, 256, 0, stream>>>(wsf, gamma, beta);

  dim3 grid(W_/16, H_/4, B_);
  if (pre) {
    w1prep<<<256, 64, 0, stream>>>(w1, w1f);
    fused_mfma<true><<<grid, 256, 0, stream>>>(x, lbpw, w1, w1f, b1, wsf, out);
  } else {
    fused_mfma<false><<<grid, 256, 0, stream>>>(x, lbpw, w1, w1f, b1, wsf, out);
  }
}

// Round 7
// 394.395 us; speedup vs baseline: 1.2912x; 1.2912x over previous
//
#include <hip/hip_runtime.h>

#define B_ 8
#define C_ 256
#define H_ 128
#define W_ 128
#define NW_ 512
#define HW_ (H_*W_)
#define EPS_ 1e-5f
#define GLIM_ (B_*C_*HW_ - 4)

typedef __attribute__((ext_vector_type(8))) short bf16x8;
typedef __attribute__((ext_vector_type(4))) float f32x4;

// RNE float -> bf16
__device__ __forceinline__ unsigned short f2bf(float f) {
  unsigned u = __float_as_uint(f);
  u += 0x7fffu + ((u >> 16) & 1u);
  return (unsigned short)(u >> 16);
}
__device__ __forceinline__ float bflo(unsigned u) { return __uint_as_float(u << 16); }
__device__ __forceinline__ float bfhi(unsigned u) { return __uint_as_float(u & 0xffff0000u); }

// async global->LDS DMA, 16B per lane, dest = wave-uniform base + lane*16
__device__ __forceinline__ void gld_lds16(const float* g, float* l) {
  __builtin_amdgcn_global_load_lds((const __attribute__((address_space(1))) void*)g,
                                   (__attribute__((address_space(3))) void*)l, 16, 0, 0);
}

// ---------- BN stats, two-stage ----------
__global__ __launch_bounds__(256)
void bn_partial(const float* __restrict__ x, float* __restrict__ psum,
                float* __restrict__ psq) {
  const int b = blockIdx.x, c = blockIdx.y, tid = threadIdx.x;
  const float4* p = (const float4*)(x + (size_t)(b*C_ + c) * HW_);
  float s = 0.f, s2 = 0.f;
  #pragma unroll
  for (int i = 0; i < 16; ++i) {
    float4 v = p[tid + i*256];
    s  += v.x + v.y + v.z + v.w;
    s2 += v.x*v.x + v.y*v.y + v.z*v.z + v.w*v.w;
  }
  #pragma unroll
  for (int off = 32; off > 0; off >>= 1) {
    s  += __shfl_down(s, off);
    s2 += __shfl_down(s2, off);
  }
  __shared__ float rs[4], rq[4];
  if ((tid & 63) == 0) { rs[tid >> 6] = s; rq[tid >> 6] = s2; }
  __syncthreads();
  if (tid == 0) {
    float S = rs[0]+rs[1]+rs[2]+rs[3], S2 = rq[0]+rq[1]+rq[2]+rq[3];
    psum[c*B_ + b] = S;
    psq [c*B_ + b] = S2;
  }
}

__global__ __launch_bounds__(256)
void bn_final(float* __restrict__ wsf, const float* __restrict__ gamma,
              const float* __restrict__ beta) {
  const int c = threadIdx.x;
  float S = 0.f, S2 = 0.f;
  #pragma unroll
  for (int b = 0; b < B_; ++b) { S += wsf[512 + c*B_ + b]; S2 += wsf[2560 + c*B_ + b]; }
  const float n = (float)(B_*HW_);
  float mean = S / n;
  float var  = S2 / n - mean*mean;
  float scl  = gamma[c] * rsqrtf(var + EPS_);
  wsf[c]       = scl;
  wsf[C_ + c]  = beta[c] - mean*scl;
}

// ---------- w1 -> bf16 A-fragment table ----------
__global__ __launch_bounds__(64)
void w1prep(const float* __restrict__ w1, ushort* __restrict__ w1f) {
  const int l15 = threadIdx.x & 15, quad = threadIdx.x >> 4;
  const int mtG = blockIdx.x >> 4, ks = blockIdx.x & 15;
  const float* src = w1 + (size_t)(mtG*16 + l15)*NW_ + ks*32 + quad*8;
  float4 f0 = *(const float4*)src, f1 = *(const float4*)(src + 4);
  union { unsigned u[4]; uint4 q; } cv;
  cv.u[0] = (unsigned)f2bf(f0.x) | ((unsigned)f2bf(f0.y) << 16);
  cv.u[1] = (unsigned)f2bf(f0.z) | ((unsigned)f2bf(f0.w) << 16);
  cv.u[2] = (unsigned)f2bf(f1.x) | ((unsigned)f2bf(f1.y) << 16);
  cv.u[3] = (unsigned)f2bf(f1.z) | ((unsigned)f2bf(f1.w) << 16);
  ((uint4*)w1f)[blockIdx.x*64 + threadIdx.x] = cv.q;
}

// ---------- fused: dw3x3(raw x) + BN-at-exit + relu + 1x1 (MFMA) + residual ----------
// r7: back to r5 skeleton (wave owns 64ch x 64px, 4 A-frags/wave), with:
//  - raw-x staging by global_load_lds DMA (BN folded to dwconv exit: scl*A + sh*S[o])
//  - xn is wave-channel-private (wave w stages & reads only ch 4w..4w+3)
//    -> only cross-wave LDS is yT -> raw s_barrier + lgkmcnt(0); DMA rides across
//    the barrier with counted vmcnt(6) (never drained to 0 in the loop)
//  - LDS 37888 B, regs 64+64 -> __launch_bounds__(256,4) = 4 blocks/CU, 16 waves
//  - yT slot-XOR swizzle (bfr ds_read_b128 was 8-way bank conflicted -> 2-way)
// Tile rows pitch 20 floats = 5 DMA slots: cols w0-1 .. w0+18 (cols 18,19 garbage;
// left/right edge cols killed by cndmask; one OOB-low corner lane patched in prologue,
// OOB-high clamped to GLIM each chunk).
template<bool PREW1>
__global__ __launch_bounds__(256, 4)
void fused_mfma(const float* __restrict__ x, const float* __restrict__ lbpw,
                const float* __restrict__ w1raw, const ushort* __restrict__ w1f,
                const float* __restrict__ b1, const float* __restrict__ sc_sh,
                float* __restrict__ out) {
  const int tid  = threadIdx.x;
  const int b    = blockIdx.z;
  const int h0   = blockIdx.y * 4;
  const int w0   = blockIdx.x * 16;
  const int wv   = tid >> 6;
  const int lane = tid & 63;
  const int l15  = lane & 15;
  const int quad = lane >> 4;
  const int cl   = tid >> 4;   // dwconv: channel slice 0..15 (= wave-aligned: wv*4..wv*4+3)
  const int jj   = tid & 15;   // dwconv: output column 0..15

  __shared__ __align__(16) float    s_xn[2][1920];     // dbuf raw-x tile: 16ch x 6r x 20cols
  __shared__ __align__(16) ushort   s_yT[2][64][40];   // dbuf y^T [px][o_local], slot-XOR swz
  __shared__ __align__(16) ushort   s_wpA[256][16];    // lbp pair-words, taps 0..7
  __shared__ __align__(16) unsigned s_wpB[256];        // lbp pair-word, tap 8
  __shared__ __align__(16) float    s_cc[768];         // per cin: {scl, sh*S_even, sh*S_odd}

  // ---- one-time tables: weight pairs + exit-scale constants ----
  {
    const float* wp0 = lbpw + (size_t)(2*tid)*9;
    float S0 = 0.f, S1 = 0.f;
    #pragma unroll
    for (int t = 0; t < 9; ++t) {
      const float we = wp0[t], wo = wp0[9 + t];
      S0 += we; S1 += wo;
      if (t < 8) {
        s_wpA[tid][2*t]   = f2bf(we);
        s_wpA[tid][2*t+1] = f2bf(wo);
      } else {
        s_wpB[tid] = (unsigned)f2bf(we) | ((unsigned)f2bf(wo) << 16);
      }
    }
    const float scl = sc_sh[tid];
    const float sh  = sc_sh[C_ + tid];
    s_cc[tid*3 + 0] = scl;
    s_cc[tid*3 + 1] = sh * S0;
    s_cc[tid*3 + 2] = sh * S1;
  }

  // ---- DMA slot geometry (wave-private: wave wv owns slots wv*120 .. wv*120+119) ----
  // slot S: ch=S/30, r=(S%30)/5, q=S%5 -> LDS floats S*4..S*4+3 (layout is slot-linear),
  // global = (b*C+ch)*HW + (h0-1+r)*W + (w0-1) + 4q, valid iff row in range.
  const int S0i = wv*120 + lane;
  const int ch0 = S0i/30, re0 = S0i - ch0*30;
  const int r0 = re0/5, q0 = re0 - r0*5;
  const int hh0 = h0 - 1 + r0;
  const bool v0 = (hh0 >= 0) && (hh0 < H_);
  const int gSb0 = ((b*C_ + ch0)*HW_) + hh0*W_ + (w0 - 1) + 4*q0;
  const bool hasS1 = (lane < 56);
  const int S1i = wv*120 + 64 + lane;
  const int ch1 = S1i/30, re1 = S1i - ch1*30;
  const int r1 = re1/5, q1 = re1 - r1*5;
  const int hh1 = h0 - 1 + r1;
  const bool v1 = hasS1 && (hh1 >= 0) && (hh1 < H_);
  const int gSb1 = ((b*C_ + ch1)*HW_) + hh1*W_ + (w0 - 1) + 4*q1;

  // pre-zero row-invalid slots in both buffers (own slots; never rewritten)
  {
    const float4 z4 = {0.f, 0.f, 0.f, 0.f};
    if (!v0) { *(float4*)&s_xn[0][S0i*4] = z4; *(float4*)&s_xn[1][S0i*4] = z4; }
    if (hasS1 && !v1) { *(float4*)&s_xn[0][S1i*4] = z4; *(float4*)&s_xn[1][S1i*4] = z4; }
  }

  // ---- acc init = b1 (bias folded) ----
  f32x4 acc[4][4];
  #pragma unroll
  for (int mt = 0; mt < 4; ++mt) {
    const f32x4 bv = *(const f32x4*)(b1 + wv*64 + mt*16 + quad*4);
    #pragma unroll
    for (int nt = 0; nt < 4; ++nt) acc[mt][nt] = bv;
  }

  __syncthreads();   // tables visible (drains everything; one-time)

  // ---- prologue: DMA chunk 0 into buf 0; patch the one OOB-low corner lane ----
  const bool patch = v0 && (gSb0 < 0);   // only block(0,0,0), wave0 lane5
  {
    float* lb = &s_xn[0][wv*480];
    if (v0 && !patch) gld_lds16(x + gSb0, lb);
    if (v1)           gld_lds16(x + gSb1, lb + 256);
    if (patch) {
      s_xn[0][S0i*4 + 0] = 0.f;     // col w=-1
      s_xn[0][S0i*4 + 1] = x[0];
      s_xn[0][S0i*4 + 2] = x[1];
      s_xn[0][S0i*4 + 3] = x[2];
    }
  }

  const bool killL = (blockIdx.x == 0) && (jj == 0);
  const bool killR = (blockIdx.x == (W_/16 - 1)) && (jj == 15);
  const int  uofs  = ((cl >> 2) ^ (jj & 3))*8 + 2*(cl & 3);   // yT write swizzle
  const int  rofs  = (quad ^ (l15 & 3))*8;                    // yT read swizzle

  #pragma unroll 2
  for (int kc = 0; kc < 16; ++kc) {
    const int p = kc & 1;

    // ---- A: w1 fragment loads for THIS chunk (in flight under dwconv) ----
    uint4 w1q[4];
    if constexpr (PREW1) {
      #pragma unroll
      for (int mt = 0; mt < 4; ++mt)
        w1q[mt] = *(const uint4*)(w1f + (size_t)(((wv*4 + mt)*16 + kc)*64 + lane)*8);
    }
    __builtin_amdgcn_sched_barrier(0);

    // ---- B: DMA stage chunk kc+1 -> xn[p^1] (rides across the barrier) ----
    if (kc < 15) {
      const int coff = (kc + 1)*(16*HW_);
      float* lb = &s_xn[p ^ 1][wv*480];
      int ga = gSb0 + coff; if (ga > GLIM_) ga = GLIM_;
      if (v0) gld_lds16(x + ga, lb);
      int gb = gSb1 + coff; if (gb > GLIM_) gb = GLIM_;
      if (v1) gld_lds16(x + gb, lb + 256);
    }
    __builtin_amdgcn_sched_barrier(0);

    // stage for THIS chunk (issued last body, 2 oldest vmem) must be complete;
    // keep this body's w1q(4)+stage(2) in flight.
    if (kc < 15) asm volatile("s_waitcnt vmcnt(6)" ::: "memory");
    else         asm volatile("s_waitcnt vmcnt(4)" ::: "memory");
    __builtin_amdgcn_sched_barrier(0);

    // ---- C: dwconv 3x3 on raw x, BN at exit, relu, pack -> yT[p] ----
    {
      const int cinG = kc*16 + cl;
      const uint4 wa = *(const uint4*)&s_wpA[cinG][0];
      const uint4 wb = *(const uint4*)&s_wpA[cinG][8];
      const unsigned w8 = s_wpB[cinG];
      const unsigned wt[9] = { wa.x, wa.y, wa.z, wa.w, wb.x, wb.y, wb.z, wb.w, w8 };
      const float* cp = &s_cc[cinG*3];
      const float scl = cp[0], sb0 = cp[1], sb1 = cp[2];

      float A0[4] = {0.f,0.f,0.f,0.f}, A1[4] = {0.f,0.f,0.f,0.f};
      const float* xb = &s_xn[p][cl*120 + jj];
      #pragma unroll
      for (int rr = 0; rr < 6; ++rr) {
        float va = xb[rr*20 + 0];
        const float vb = xb[rr*20 + 1];
        float vc = xb[rr*20 + 2];
        if (killL) va = 0.f;
        if (killR) vc = 0.f;
        #pragma unroll
        for (int r = 0; r < 4; ++r) {
          const int di = rr - r;
          if (di >= 0 && di < 3) {
            A0[r] = fmaf(bflo(wt[di*3+2]), vc, fmaf(bflo(wt[di*3+1]), vb, fmaf(bflo(wt[di*3+0]), va, A0[r])));
            A1[r] = fmaf(bfhi(wt[di*3+2]), vc, fmaf(bfhi(wt[di*3+1]), vb, fmaf(bfhi(wt[di*3+0]), va, A1[r])));
          }
        }
      }
      #pragma unroll
      for (int r = 0; r < 4; ++r) {
        const float y0 = fmaxf(fmaf(scl, A0[r], sb0), 0.f);
        const float y1 = fmaxf(fmaf(scl, A1[r], sb1), 0.f);
        *(unsigned*)&s_yT[p][r*16 + jj][uofs] =
            (unsigned)f2bf(y0) | ((unsigned)f2bf(y1) << 16);
      }
    }

    // yT visible to all waves; DMAs stay in flight (no vmcnt drain!)
    asm volatile("s_waitcnt lgkmcnt(0)" ::: "memory");
    __builtin_amdgcn_s_barrier();

    // ---- D: GEMM: acc[ch][px] += w1[ch][o] * y[o][px], K=32 ----
    bf16x8 bfr[4];
    #pragma unroll
    for (int nt = 0; nt < 4; ++nt)
      bfr[nt] = *(const bf16x8*)&s_yT[p][nt*16 + l15][rofs];

    #pragma unroll
    for (int mt = 0; mt < 4; ++mt) {
      bf16x8 afr;
      if constexpr (PREW1) {
        union { uint4 q; bf16x8 v; } cv;
        cv.q = w1q[mt];
        afr = cv.v;
      } else {
        const float* wp = w1raw + (size_t)(wv*64 + mt*16 + l15)*NW_ + kc*32 + quad*8;
        const float4 f0 = *(const float4*)wp;
        const float4 f1 = *(const float4*)(wp + 4);
        union { unsigned u[4]; bf16x8 v; } cv;
        cv.u[0] = (unsigned)f2bf(f0.x) | ((unsigned)f2bf(f0.y) << 16);
        cv.u[1] = (unsigned)f2bf(f0.z) | ((unsigned)f2bf(f0.w) << 16);
        cv.u[2] = (unsigned)f2bf(f1.x) | ((unsigned)f2bf(f1.y) << 16);
        cv.u[3] = (unsigned)f2bf(f1.z) | ((unsigned)f2bf(f1.w) << 16);
        afr = cv.v;
      }
      #pragma unroll
      for (int nt = 0; nt < 4; ++nt)
        acc[mt][nt] = __builtin_amdgcn_mfma_f32_16x16x32_bf16(afr, bfr[nt], acc[mt][nt], 0, 0, 0);
    }
  }

  // ---- epilogue: + raw-x residual (b1 folded into acc init) ----
  #pragma unroll
  for (int mt = 0; mt < 4; ++mt) {
    #pragma unroll
    for (int nt = 0; nt < 4; ++nt) {
      const int h = h0 + nt;
      #pragma unroll
      for (int i = 0; i < 4; ++i) {
        const int ch = wv*64 + mt*16 + quad*4 + i;
        const size_t o = ((size_t)(b*C_ + ch)*H_ + h)*W_ + (w0 + l15);
        out[o] = acc[mt][nt][i] + x[o];
      }
    }
  }
}

extern "C" void kernel_launch(void* const* d_in, const int* in_sizes, int n_in,
                              void* d_out, int out_size, void* d_ws, size_t ws_size,
                              hipStream_t stream) {
  const float* x     = (const float*)d_in[0];
  const float* gamma = (const float*)d_in[1];
  const float* beta  = (const float*)d_in[2];
  const float* lbpw  = (const float*)d_in[3];
  const float* w1    = (const float*)d_in[4];
  const float* b1    = (const float*)d_in[5];
  float* out = (float*)d_out;

  // ws layout (floats): [0,256) scale | [256,512) shift | [512,2560) psum |
  //                     [2560,4608) psq | byte 18432: w1 bf16 frag table (256 KB)
  float* wsf = (float*)d_ws;
  ushort* w1f = (ushort*)((char*)d_ws + 18432);
  const bool pre = ws_size >= (size_t)(18432 + 262144);

  bn_partial<<<dim3(B_, C_), 256, 0, stream>>>(x, wsf + 512, wsf + 2560);
  bn_final<<<1, 256, 0, stream>>>(wsf, gamma, beta);

  dim3 grid(W_/16, H_/4, B_);
  if (pre) {
    w1prep<<<256, 64, 0, stream>>>(w1, w1f);
    fused_mfma<true><<<grid, 256, 0, stream>>>(x, lbpw, w1, w1f, b1, wsf, out);
  } else {
    fused_mfma<false><<<grid, 256, 0, stream>>>(x, lbpw, w1, w1f, b1, wsf, out);
  }
}